// Round 4
// baseline (1795.816 us; speedup 1.0000x reference)
//
#include <hip/hip_runtime.h>
#include <hip/hip_bf16.h>
#include <cstdint>

// Fused LISTA v3: block = 64 batch rows, 512 threads (8 waves x 128 cols).
// Z tile in LDS (128 KB, XOR-swizzled — correctness verified R1/R2/R3).
// R2/R3 failed on scratch spill (~465 MB/dispatch writes): compiler unrolled
// the kc loop and hoisted whole windows of S-fragment loads past the 128-reg
// arch budget. v3 pins the pipeline shape:
//  - '#pragma unroll 1' kc loop, hand-written even/odd 2-stage pipeline with
//    STATICALLY indexed sbE[8]/sbO[8] (no addressable array, no unroll blowup)
//  - minimal-live epilogue (Bws packets loaded one mi at a time)
//  - nontemporal Bws/out traffic so streamed data doesn't evict S from L2

typedef __attribute__((ext_vector_type(8))) short short8;   // 8 x bf16
typedef __attribute__((ext_vector_type(4))) float floatx4;  // mfma acc
typedef __attribute__((ext_vector_type(4))) unsigned int uintx4;

__device__ __forceinline__ unsigned short f2b(float f) {
    __hip_bfloat16 h = __float2bfloat16(f);
    return *(unsigned short*)&h;
}
__device__ __forceinline__ float b2f(unsigned short u) {
    union { unsigned int i; float f; } x; x.i = ((unsigned int)u) << 16; return x.f;
}

__global__ void __launch_bounds__(512, 2)
lista_fused(const unsigned short* __restrict__ Xbf,   // 16384 x 256
            const unsigned short* __restrict__ Webf,  // 1024 x 256
            const unsigned short* __restrict__ Sbf,   // 1024 x 1024
            const float* __restrict__ theta,          // 1024
            uintx4* __restrict__ Bws,                 // packed B tile, 32 MB
            float* __restrict__ out)                  // 16384 x 1024 fp32
{
    __shared__ __align__(16) unsigned short Zd[64 * 1024];  // 128 KB

    const int t    = threadIdx.x;
    const int wave = t >> 6;        // 0..7, owns cols [wave*128, +128)
    const int lane = t & 63;
    const int l15  = lane & 15;
    const int q    = lane >> 4;
    const int blk  = blockIdx.x;    // 0..255, owns rows [blk*64, +64)

    floatx4 acc[4][8];              // 128 regs (accumulator)
#pragma unroll
    for (int mi = 0; mi < 4; ++mi)
#pragma unroll
        for (int ni = 0; ni < 8; ++ni) acc[mi][ni] = (floatx4){0.f, 0.f, 0.f, 0.f};

    // A/B-operand frag layout: lane -> 16B at [m|n = l15][k = q*8 .. q*8+7]
    const char* Sb = (const char*)Sbf  + ((size_t)(wave * 128 + l15) * 1024 + q * 8) * 2;
    const char* Xb = (const char*)Xbf  + ((size_t)(blk * 64   + l15) * 256  + q * 8) * 2;
    const char* Wb = (const char*)Webf + ((size_t)(wave * 128 + l15) * 256  + q * 8) * 2;

    // ---- init GEMM: acc = X @ We^T (K=256). One-shot; latency irrelevant. ----
#pragma unroll 1
    for (int kc = 0; kc < 8; ++kc) {
        short8 af[4], sf[8];
#pragma unroll
        for (int mi = 0; mi < 4; ++mi)
            af[mi] = *(const short8*)(Xb + mi * 8192 + kc * 64);
#pragma unroll
        for (int ni = 0; ni < 8; ++ni)
            sf[ni] = *(const short8*)(Wb + ni * 8192 + kc * 64);
#pragma unroll
        for (int mi = 0; mi < 4; ++mi)
#pragma unroll
            for (int ni = 0; ni < 8; ++ni)
                acc[mi][ni] = __builtin_amdgcn_mfma_f32_16x16x32_bf16(
                    af[mi], sf[ni], acc[mi][ni], 0, 0, 0);
    }

    float th[8];
#pragma unroll
    for (int ni = 0; ni < 8; ++ni) th[ni] = theta[wave * 128 + ni * 16 + l15];

    // ---- init epilogue: Bws = pack(B) [NT]; Z0 = eta(B) -> LDS; acc := round(B) ----
#pragma unroll
    for (int mi = 0; mi < 4; ++mi) {
#pragma unroll
        for (int c = 0; c < 4; ++c) {
            uintx4 pk;
#pragma unroll
            for (int e = 0; e < 4; ++e) {
                const int j0 = c * 8 + e * 2, j1 = j0 + 1;
                const unsigned short b0 = f2b(acc[mi][j0 >> 2][j0 & 3]);
                const unsigned short b1 = f2b(acc[mi][j1 >> 2][j1 & 3]);
                pk[e] = (unsigned int)b0 | ((unsigned int)b1 << 16);
            }
            __builtin_nontemporal_store(pk, &Bws[(size_t)((blk * 4 + mi) * 4 + c) * 512 + t]);
        }
#pragma unroll
        for (int ni = 0; ni < 8; ++ni) {
            const int col   = wave * 128 + ni * 16 + l15;
            const int chunk = col >> 3;
            const int coff  = (col & 7) * 2;
#pragma unroll
            for (int v = 0; v < 4; ++v) {
                const unsigned short bb = f2b(acc[mi][ni][v]);
                const float c0 = b2f(bb);
                acc[mi][ni][v] = c0;                 // acc := rounded B
                const float a = fabsf(c0) - th[ni];
                const float z = a > 0.f ? copysignf(a, c0) : 0.f;
                const int r = mi * 16 + q * 4 + v;
                const int s = (chunk & ~7) | ((chunk ^ r) & 7);
                *(unsigned short*)((char*)Zd + r * 2048 + s * 16 + coff) = f2b(z);
            }
        }
    }
    __syncthreads();

    // ---- 16 fused steps ----
#pragma unroll 1
    for (int step = 1; step <= 16; ++step) {
        short8 sbE[8], sbO[8];      // static even/odd S-frag buffers (64 regs)
#pragma unroll
        for (int ni = 0; ni < 8; ++ni)
            sbE[ni] = *(const short8*)(Sb + ni * 32768);    // kc = 0

#pragma unroll 1
        for (int kc = 0; kc < 32; kc += 2) {
            // prefetch odd slice kc+1 before consuming even slice kc
#pragma unroll
            for (int ni = 0; ni < 8; ++ni)
                sbO[ni] = *(const short8*)(Sb + ni * 32768 + (kc + 1) * 64);
            {
                short8 af[4];
#pragma unroll
                for (int mi = 0; mi < 4; ++mi) {
                    const int row = mi * 16 + l15;
                    const int c   = kc * 4 + q;
                    const int s   = (c & ~7) | ((c ^ row) & 7);
                    af[mi] = *(const short8*)((const char*)Zd + row * 2048 + s * 16);
                }
#pragma unroll
                for (int mi = 0; mi < 4; ++mi)
#pragma unroll
                    for (int ni = 0; ni < 8; ++ni)
                        acc[mi][ni] = __builtin_amdgcn_mfma_f32_16x16x32_bf16(
                            af[mi], sbE[ni], acc[mi][ni], 0, 0, 0);
            }
            // prefetch even slice kc+2 (wraps to 0 on last iter — harmless)
#pragma unroll
            for (int ni = 0; ni < 8; ++ni)
                sbE[ni] = *(const short8*)(Sb + ni * 32768 + ((kc + 2) & 31) * 64);
            {
                short8 af[4];
#pragma unroll
                for (int mi = 0; mi < 4; ++mi) {
                    const int row = mi * 16 + l15;
                    const int c   = (kc + 1) * 4 + q;
                    const int s   = (c & ~7) | ((c ^ row) & 7);
                    af[mi] = *(const short8*)((const char*)Zd + row * 2048 + s * 16);
                }
#pragma unroll
                for (int mi = 0; mi < 4; ++mi)
#pragma unroll
                    for (int ni = 0; ni < 8; ++ni)
                        acc[mi][ni] = __builtin_amdgcn_mfma_f32_16x16x32_bf16(
                            af[mi], sbO[ni], acc[mi][ni], 0, 0, 0);
            }
        }
        __syncthreads();   // all waves done reading old Z

        if (step < 16) {
#pragma unroll
            for (int mi = 0; mi < 4; ++mi) {
                // (a) eta(acc) -> LDS (reads acc)
#pragma unroll
                for (int ni = 0; ni < 8; ++ni) {
                    const int col   = wave * 128 + ni * 16 + l15;
                    const int chunk = col >> 3;
                    const int coff  = (col & 7) * 2;
#pragma unroll
                    for (int v = 0; v < 4; ++v) {
                        const float cv = acc[mi][ni][v];
                        const float a  = fabsf(cv) - th[ni];
                        const float z  = a > 0.f ? copysignf(a, cv) : 0.f;
                        const int r = mi * 16 + q * 4 + v;
                        const int s = (chunk & ~7) | ((chunk ^ r) & 7);
                        *(unsigned short*)((char*)Zd + r * 2048 + s * 16 + coff) = f2b(z);
                    }
                }
                // (b) acc := B, one 16B packet at a time (minimal live regs)
#pragma unroll
                for (int c = 0; c < 4; ++c) {
                    const uintx4 pk = __builtin_nontemporal_load(
                        &Bws[(size_t)((blk * 4 + mi) * 4 + c) * 512 + t]);
#pragma unroll
                    for (int e = 0; e < 4; ++e) {
                        const int j0 = c * 8 + e * 2, j1 = j0 + 1;
                        acc[mi][j0 >> 2][j0 & 3] = b2f((unsigned short)(pk[e] & 0xffff));
                        acc[mi][j1 >> 2][j1 & 3] = b2f((unsigned short)(pk[e] >> 16));
                    }
                }
            }
            __syncthreads();   // new Z visible before next step reads
        } else {
#pragma unroll
            for (int mi = 0; mi < 4; ++mi)
#pragma unroll
                for (int ni = 0; ni < 8; ++ni) {
                    const int col = wave * 128 + ni * 16 + l15;
#pragma unroll
                    for (int v = 0; v < 4; ++v) {
                        const float cv = acc[mi][ni][v];
                        const float a  = fabsf(cv) - th[ni];
                        const float z  = a > 0.f ? copysignf(a, cv) : 0.f;
                        const int r = mi * 16 + q * 4 + v;
                        __builtin_nontemporal_store(
                            z, &out[(size_t)(blk * 64 + r) * 1024 + col]);
                    }
                }
        }
    }
}

__global__ void __launch_bounds__(256)
cvt4(const float* __restrict__ s, unsigned short* __restrict__ d, int n4)
{
    const int i = blockIdx.x * blockDim.x + threadIdx.x;
    if (i < n4) {
        const float4 v = ((const float4*)s)[i];
        ushort4 o;
        o.x = f2b(v.x); o.y = f2b(v.y); o.z = f2b(v.z); o.w = f2b(v.w);
        ((ushort4*)d)[i] = o;
    }
}

extern "C" void kernel_launch(void* const* d_in, const int* in_sizes, int n_in,
                              void* d_out, int out_size, void* d_ws, size_t ws_size,
                              hipStream_t stream) {
    const float* X     = (const float*)d_in[0];  // 16384 x 256
    const float* We    = (const float*)d_in[1];  // 1024 x 256
    const float* S     = (const float*)d_in[2];  // 1024 x 1024
    const float* theta = (const float*)d_in[3];  // 1024
    float* out = (float*)d_out;                  // 16384 x 1024 fp32

    char* ws = (char*)d_ws;
    unsigned short* S_bf  = (unsigned short*)(ws);                          // 2 MB
    unsigned short* X_bf  = (unsigned short*)(ws + (size_t)3  * 1048576);   // 8 MB
    unsigned short* We_bf = (unsigned short*)(ws + (size_t)11 * 1048576);   // 0.5 MB
    uintx4*         Bws   = (uintx4*)        (ws + (size_t)12 * 1048576);   // 32 MB

    cvt4<<<dim3(1024), dim3(256), 0, stream>>>(S,  S_bf,  1024 * 1024 / 4);
    cvt4<<<dim3(4096), dim3(256), 0, stream>>>(X,  X_bf,  16384 * 256 / 4);
    cvt4<<<dim3(256),  dim3(256), 0, stream>>>(We, We_bf, 1024 * 256 / 4);

    lista_fused<<<dim3(256), dim3(512), 0, stream>>>(X_bf, We_bf, S_bf, theta, Bws, out);
}

// Round 5
// 1763.060 us; speedup vs baseline: 1.0186x; 1.0186x over previous
//
#include <hip/hip_runtime.h>
#include <hip/hip_bf16.h>
#include <cstdint>

// Fused LISTA v4: block = 64 batch rows, 512 threads (8 waves x 128 cols).
// Z tile in LDS (128 KB, XOR-swizzled). R2-R4 all scratch-spilled (~450 MB
// writes/dispatch) because live set was ~258 > 256 unified regs (2 waves/SIMD):
// 16 VGPRs of 64-bit S-address pairs + unbounded load hoisting pushed it over.
// v4: (a) wave-uniform SGPR base pointers + ONE per-lane voffset for S/X/We
// loads (saves ~15 VGPRs); (b) sched_barrier(0) at each even/odd phase
// boundary caps in-flight loads at one 8-load phase; (c) af loaded per-mi.
// Steady live ~= acc 128 + sb 64 + af 16 + ~25 misc = ~232 < 256.

typedef __attribute__((ext_vector_type(8))) short short8;   // 8 x bf16
typedef __attribute__((ext_vector_type(4))) float floatx4;  // mfma acc
typedef __attribute__((ext_vector_type(4))) unsigned int uintx4;

__device__ __forceinline__ unsigned short f2b(float f) {
    __hip_bfloat16 h = __float2bfloat16(f);
    return *(unsigned short*)&h;
}
__device__ __forceinline__ float b2f(unsigned short u) {
    union { unsigned int i; float f; } x; x.i = ((unsigned int)u) << 16; return x.f;
}

__global__ void __launch_bounds__(512, 2)
lista_fused(const unsigned short* __restrict__ Xbf,   // 16384 x 256
            const unsigned short* __restrict__ Webf,  // 1024 x 256
            const unsigned short* __restrict__ Sbf,   // 1024 x 1024
            const float* __restrict__ theta,          // 1024
            uintx4* __restrict__ Bws,                 // packed B tile, 32 MB
            float* __restrict__ out)                  // 16384 x 1024 fp32
{
    __shared__ __align__(16) unsigned short Zd[64 * 1024];  // 128 KB

    const int t    = threadIdx.x;
    const int wave = t >> 6;        // 0..7, owns cols [wave*128, +128)
    const int lane = t & 63;
    const int l15  = lane & 15;
    const int q    = lane >> 4;
    const int blk  = blockIdx.x;    // 0..255, owns rows [blk*64, +64)

    floatx4 acc[4][8];              // 128 regs (accumulator)
#pragma unroll
    for (int mi = 0; mi < 4; ++mi)
#pragma unroll
        for (int ni = 0; ni < 8; ++ni) acc[mi][ni] = (floatx4){0.f, 0.f, 0.f, 0.f};

    // --- wave-uniform base pointers (SGPRs) + single per-lane voffsets ---
    // S frag (ni): row = wave*128 + ni*16 + l15, k = q*8  ->
    //   byte = ni*32768 + (wave*128+l15)*2048 + q*16 + kc*64
    const char* Sp[8];
#pragma unroll
    for (int ni = 0; ni < 8; ++ni) Sp[ni] = (const char*)Sbf + ni * 32768;
    const unsigned svo = (unsigned)((wave * 128 + l15) * 2048 + q * 16);

    // We frag (ni): row = wave*128 + ni*16 + l15, k = q*8 (K=256) ->
    //   byte = ni*8192 + (wave*128+l15)*512 + q*16 + kc*64
    const unsigned wvo = (unsigned)((wave * 128 + l15) * 512 + q * 16);
    // X frag (mi): row = blk*64 + mi*16 + l15 ->
    //   byte = blk*32768 + mi*8192 + l15*512 + q*16 + kc*64
    const char* Xp = (const char*)Xbf + (size_t)blk * 32768;
    const unsigned xvo = (unsigned)(l15 * 512 + q * 16);

    // ---- init GEMM: acc = X @ We^T (K=256). One-shot. ----
#pragma unroll 1
    for (int kc = 0; kc < 8; ++kc) {
        short8 af[4], sf[8];
#pragma unroll
        for (int mi = 0; mi < 4; ++mi)
            af[mi] = *(const short8*)(Xp + mi * 8192 + (xvo + kc * 64));
#pragma unroll
        for (int ni = 0; ni < 8; ++ni)
            sf[ni] = *(const short8*)((const char*)Webf + ni * 8192 + (wvo + kc * 64));
#pragma unroll
        for (int mi = 0; mi < 4; ++mi)
#pragma unroll
            for (int ni = 0; ni < 8; ++ni)
                acc[mi][ni] = __builtin_amdgcn_mfma_f32_16x16x32_bf16(
                    af[mi], sf[ni], acc[mi][ni], 0, 0, 0);
        __builtin_amdgcn_sched_barrier(0);
    }

    float th[8];
#pragma unroll
    for (int ni = 0; ni < 8; ++ni) th[ni] = theta[wave * 128 + ni * 16 + l15];

    // ---- init epilogue: Bws = pack(B) [NT]; Z0 = eta(B) -> LDS; acc := round(B) ----
#pragma unroll
    for (int mi = 0; mi < 4; ++mi) {
#pragma unroll
        for (int c = 0; c < 4; ++c) {
            uintx4 pk;
#pragma unroll
            for (int e = 0; e < 4; ++e) {
                const int j0 = c * 8 + e * 2, j1 = j0 + 1;
                const unsigned short b0 = f2b(acc[mi][j0 >> 2][j0 & 3]);
                const unsigned short b1 = f2b(acc[mi][j1 >> 2][j1 & 3]);
                pk[e] = (unsigned int)b0 | ((unsigned int)b1 << 16);
            }
            __builtin_nontemporal_store(pk, &Bws[(size_t)((blk * 4 + mi) * 4 + c) * 512 + t]);
        }
#pragma unroll
        for (int ni = 0; ni < 8; ++ni) {
            const int col   = wave * 128 + ni * 16 + l15;
            const int chunk = col >> 3;
            const int coff  = (col & 7) * 2;
#pragma unroll
            for (int v = 0; v < 4; ++v) {
                const unsigned short bb = f2b(acc[mi][ni][v]);
                const float c0 = b2f(bb);
                acc[mi][ni][v] = c0;                 // acc := rounded B
                const float a = fabsf(c0) - th[ni];
                const float z = a > 0.f ? copysignf(a, c0) : 0.f;
                const int r = mi * 16 + q * 4 + v;
                const int s = (chunk & ~7) | ((chunk ^ r) & 7);
                *(unsigned short*)((char*)Zd + r * 2048 + s * 16 + coff) = f2b(z);
            }
        }
    }
    __syncthreads();

    // S frag double buffer, statically indexed. Slice 0 preloaded once; the
    // odd-phase wrap prefetch ((kc+2)&31 == 0 at kc==30) reloads slice 0 for
    // the NEXT step (S is step-invariant) — pipeline never drains.
    short8 sbE[8], sbO[8];
#pragma unroll
    for (int ni = 0; ni < 8; ++ni)
        sbE[ni] = *(const short8*)(Sp[ni] + svo);

    // ---- 16 fused steps ----
#pragma unroll 1
    for (int step = 1; step <= 16; ++step) {
#pragma unroll 1
        for (int kc = 0; kc < 32; kc += 2) {
            // even phase: prefetch slice kc+1, consume sbE (slice kc)
#pragma unroll
            for (int ni = 0; ni < 8; ++ni)
                sbO[ni] = *(const short8*)(Sp[ni] + (svo + (kc + 1) * 64));
#pragma unroll
            for (int mi = 0; mi < 4; ++mi) {
                const int row = mi * 16 + l15;
                const int c   = kc * 4 + q;
                const int s   = (c & ~7) | ((c ^ row) & 7);
                const short8 a = *(const short8*)((const char*)Zd + row * 2048 + s * 16);
#pragma unroll
                for (int ni = 0; ni < 8; ++ni)
                    acc[mi][ni] = __builtin_amdgcn_mfma_f32_16x16x32_bf16(
                        a, sbE[ni], acc[mi][ni], 0, 0, 0);
            }
            __builtin_amdgcn_sched_barrier(0);
            // odd phase: prefetch slice (kc+2)&31, consume sbO (slice kc+1)
#pragma unroll
            for (int ni = 0; ni < 8; ++ni)
                sbE[ni] = *(const short8*)(Sp[ni] + (svo + ((kc + 2) & 31) * 64));
#pragma unroll
            for (int mi = 0; mi < 4; ++mi) {
                const int row = mi * 16 + l15;
                const int c   = (kc + 1) * 4 + q;
                const int s   = (c & ~7) | ((c ^ row) & 7);
                const short8 a = *(const short8*)((const char*)Zd + row * 2048 + s * 16);
#pragma unroll
                for (int ni = 0; ni < 8; ++ni)
                    acc[mi][ni] = __builtin_amdgcn_mfma_f32_16x16x32_bf16(
                        a, sbO[ni], acc[mi][ni], 0, 0, 0);
            }
            __builtin_amdgcn_sched_barrier(0);
        }
        __syncthreads();   // all waves done reading old Z

        if (step < 16) {
#pragma unroll
            for (int mi = 0; mi < 4; ++mi) {
                // (a) eta(acc) -> LDS
#pragma unroll
                for (int ni = 0; ni < 8; ++ni) {
                    const int col   = wave * 128 + ni * 16 + l15;
                    const int chunk = col >> 3;
                    const int coff  = (col & 7) * 2;
#pragma unroll
                    for (int v = 0; v < 4; ++v) {
                        const float cv = acc[mi][ni][v];
                        const float a  = fabsf(cv) - th[ni];
                        const float z  = a > 0.f ? copysignf(a, cv) : 0.f;
                        const int r = mi * 16 + q * 4 + v;
                        const int s = (chunk & ~7) | ((chunk ^ r) & 7);
                        *(unsigned short*)((char*)Zd + r * 2048 + s * 16 + coff) = f2b(z);
                    }
                }
                // (b) acc := B, one 16B packet at a time
#pragma unroll
                for (int c = 0; c < 4; ++c) {
                    const uintx4 pk = __builtin_nontemporal_load(
                        &Bws[(size_t)((blk * 4 + mi) * 4 + c) * 512 + t]);
#pragma unroll
                    for (int e = 0; e < 4; ++e) {
                        const int j0 = c * 8 + e * 2, j1 = j0 + 1;
                        acc[mi][j0 >> 2][j0 & 3] = b2f((unsigned short)(pk[e] & 0xffff));
                        acc[mi][j1 >> 2][j1 & 3] = b2f((unsigned short)(pk[e] >> 16));
                    }
                }
            }
            __syncthreads();   // new Z visible before next step reads
        } else {
#pragma unroll
            for (int mi = 0; mi < 4; ++mi)
#pragma unroll
                for (int ni = 0; ni < 8; ++ni) {
                    const int col = wave * 128 + ni * 16 + l15;
#pragma unroll
                    for (int v = 0; v < 4; ++v) {
                        const float cv = acc[mi][ni][v];
                        const float a  = fabsf(cv) - th[ni];
                        const float z  = a > 0.f ? copysignf(a, cv) : 0.f;
                        const int r = mi * 16 + q * 4 + v;
                        __builtin_nontemporal_store(
                            z, &out[(size_t)(blk * 64 + r) * 1024 + col]);
                    }
                }
        }
    }
}

__global__ void __launch_bounds__(256)
cvt4(const float* __restrict__ s, unsigned short* __restrict__ d, int n4)
{
    const int i = blockIdx.x * blockDim.x + threadIdx.x;
    if (i < n4) {
        const float4 v = ((const float4*)s)[i];
        ushort4 o;
        o.x = f2b(v.x); o.y = f2b(v.y); o.z = f2b(v.z); o.w = f2b(v.w);
        ((ushort4*)d)[i] = o;
    }
}

extern "C" void kernel_launch(void* const* d_in, const int* in_sizes, int n_in,
                              void* d_out, int out_size, void* d_ws, size_t ws_size,
                              hipStream_t stream) {
    const float* X     = (const float*)d_in[0];  // 16384 x 256
    const float* We    = (const float*)d_in[1];  // 1024 x 256
    const float* S     = (const float*)d_in[2];  // 1024 x 1024
    const float* theta = (const float*)d_in[3];  // 1024
    float* out = (float*)d_out;                  // 16384 x 1024 fp32

    char* ws = (char*)d_ws;
    unsigned short* S_bf  = (unsigned short*)(ws);                          // 2 MB
    unsigned short* X_bf  = (unsigned short*)(ws + (size_t)3  * 1048576);   // 8 MB
    unsigned short* We_bf = (unsigned short*)(ws + (size_t)11 * 1048576);   // 0.5 MB
    uintx4*         Bws   = (uintx4*)        (ws + (size_t)12 * 1048576);   // 32 MB

    cvt4<<<dim3(1024), dim3(256), 0, stream>>>(S,  S_bf,  1024 * 1024 / 4);
    cvt4<<<dim3(4096), dim3(256), 0, stream>>>(X,  X_bf,  16384 * 256 / 4);
    cvt4<<<dim3(256),  dim3(256), 0, stream>>>(We, We_bf, 1024 * 256 / 4);

    lista_fused<<<dim3(256), dim3(512), 0, stream>>>(X_bf, We_bf, S_bf, theta, Bws, out);
}